// Round 6
// baseline (176.251 us; speedup 1.0000x reference)
//
#include <hip/hip_runtime.h>
#include <hip/hip_bf16.h>
#include <math.h>

#define NN 8192      // nodes
#define NK 64        // clusters
#define EPSF 1e-6f
#define JW 256       // cols per block (j-window)
#define TM 16        // rows per tile
#define NTILE 16     // tiles per block -> 256 rows per block
// grid: 32 j-strips x 32 i-groups = 1024 blocks (4/CU, fully resident), 256 threads

typedef __attribute__((ext_vector_type(8))) short s16x8;
typedef __attribute__((ext_vector_type(4))) short s16x4;
typedef __attribute__((ext_vector_type(4))) float f32x4;

static __device__ __forceinline__ short f2bf(float x) {
    union { float f; unsigned u; } v; v.f = x;
    unsigned r = (v.u + 0x7fffu + ((v.u >> 16) & 1u)) >> 16;
    return (short)r;
}

// ---------- pre-kernel: A [N][64] f32 -> ATF fragment-major bf16 ----------
// ATF[((chunk*4 + f)*64 + l)*8 + e] = A[chunk*32 + (l>>4)*8 + e][(l&15) + 16*f]
// so pass_e B-fragment loads are contiguous 1KB per wave instruction.
__global__ __launch_bounds__(256) void cvt_at(const float* __restrict__ A,
                                              unsigned short* __restrict__ ATF) {
    __shared__ unsigned short T[64][72];   // [k][node]
    int tid = threadIdx.x;
    int n0 = blockIdx.x * 64;
    int node = tid >> 2;
    int k4 = (tid & 3) << 4;
    const float* ap = A + (size_t)(n0 + node) * NK + k4;
    f32x4 x0 = *(const f32x4*)(ap);
    f32x4 x1 = *(const f32x4*)(ap + 4);
    f32x4 x2 = *(const f32x4*)(ap + 8);
    f32x4 x3 = *(const f32x4*)(ap + 12);
#pragma unroll
    for (int e = 0; e < 4; ++e) {
        T[k4 + e][node]      = (unsigned short)f2bf(x0[e]);
        T[k4 + 4 + e][node]  = (unsigned short)f2bf(x1[e]);
        T[k4 + 8 + e][node]  = (unsigned short)f2bf(x2[e]);
        T[k4 + 12 + e][node] = (unsigned short)f2bf(x3[e]);
    }
    __syncthreads();
#pragma unroll
    for (int pass = 0; pass < 2; ++pass) {
        int oi = pass * 256 + tid;          // 512 outputs of 16B
        int l = oi & 63, f = (oi >> 6) & 3, cl = oi >> 8;
        int k = (l & 15) + 16 * f;
        int nb = cl * 32 + (l >> 4) * 8;
        s16x8 v;
#pragma unroll
        for (int e = 0; e < 8; ++e) v[e] = (short)T[k][nb + e];
        size_t chunk = (size_t)blockIdx.x * 2 + cl;
        *(s16x8*)(ATF + ((chunk * 4 + f) * 64 + l) * 8) = v;
    }
}

// ---------- main fused pass over E: 1-barrier/tile software pipeline ----------
__global__ __launch_bounds__(256, 4) void pass_e(
    const float* __restrict__ E, const float* __restrict__ A,
    const unsigned short* __restrict__ ATF,
    float* __restrict__ rowsum, float* __restrict__ colsum,
    float* __restrict__ within_part)
{
    __shared__ unsigned short Ebf[2][TM * JW];  // 2 x 8KB, swizzled rows of 512B
    __shared__ float csum[4][JW];               // 4KB
    __shared__ float red[4];

    int tid = threadIdx.x;
    int w = tid >> 6, l = tid & 63;
    int bid = blockIdx.x;
    int jstrip = bid & 31;
    int ig = bid >> 5;
    int jbase = jstrip * JW;
    int ibase = ig * (TM * NTILE);
    int lm = l & 15, lg = l >> 4;
    int chunk0 = jstrip * 8;                    // 8 j-chunks of 32 per window

    float creg0 = 0.f, creg1 = 0.f, creg2 = 0.f, creg3 = 0.f;
    float wsum = 0.f;
    s16x8 ONES;
#pragma unroll
    for (int e = 0; e < 8; ++e) ONES[e] = (short)0x3F80;  // bf16 1.0

    // wave stages rows 4w..4w+3 of each tile; lane covers cols 4l..4l+3
    const float* p = E + (size_t)(ibase + 4 * w) * NN + jbase + 4 * l;
    int wr = 4 * w;                              // first staged row (tile-local)
    unsigned swz0 = (l * 8) ^ (((wr + 0) & 7) << 4);
    unsigned swz1 = (l * 8) ^ (((wr + 1) & 7) << 4);
    unsigned swz2 = (l * 8) ^ (((wr + 2) & 7) << 4);
    unsigned swz3 = (l * 8) ^ (((wr + 3) & 7) << 4);

    f32x4 ld0 = *(const f32x4*)(p + 0 * (size_t)NN);
    f32x4 ld1 = *(const f32x4*)(p + 1 * (size_t)NN);
    f32x4 ld2 = *(const f32x4*)(p + 2 * (size_t)NN);
    f32x4 ld3 = *(const f32x4*)(p + 3 * (size_t)NN);

    for (int t = 0; t < NTILE; ++t) {
        // ---- stage tile t: colsum in regs, cvt, ds_write to buf[t&1] ----
        char* buf = (char*)&Ebf[t & 1][0];
        creg0 += ld0[0] + ld1[0] + ld2[0] + ld3[0];
        creg1 += ld0[1] + ld1[1] + ld2[1] + ld3[1];
        creg2 += ld0[2] + ld1[2] + ld2[2] + ld3[2];
        creg3 += ld0[3] + ld1[3] + ld2[3] + ld3[3];
        s16x4 b0, b1, b2, b3;
#pragma unroll
        for (int e = 0; e < 4; ++e) {
            b0[e] = f2bf(ld0[e]); b1[e] = f2bf(ld1[e]);
            b2[e] = f2bf(ld2[e]); b3[e] = f2bf(ld3[e]);
        }
        *(s16x4*)(buf + (wr + 0) * 512 + swz0) = b0;
        *(s16x4*)(buf + (wr + 1) * 512 + swz1) = b1;
        *(s16x4*)(buf + (wr + 2) * 512 + swz2) = b2;
        *(s16x4*)(buf + (wr + 3) * 512 + swz3) = b3;

        // ---- issue loads for tile t+1 (stay in flight across the barrier) ----
        if (t + 1 < NTILE) {
            const float* pn = p + (size_t)(16 * (t + 1)) * NN;
            ld0 = *(const f32x4*)(pn + 0 * (size_t)NN);
            ld1 = *(const f32x4*)(pn + 1 * (size_t)NN);
            ld2 = *(const f32x4*)(pn + 2 * (size_t)NN);
            ld3 = *(const f32x4*)(pn + 3 * (size_t)NN);
        }
        __builtin_amdgcn_sched_barrier(0);            // pin loads before barrier
        asm volatile("s_waitcnt lgkmcnt(0)" ::: "memory");
        __builtin_amdgcn_s_barrier();                 // raw: no vmcnt drain
        __builtin_amdgcn_sched_barrier(0);            // no ds_read hoist (rule 18)

        // ---- MFMA phase: wave owns j-chunks 2w, 2w+1 of this tile ----
        f32x4 D0 = {0.f,0.f,0.f,0.f}, D1 = D0, D2 = D0, D3 = D0, Dr = D0;
#pragma unroll
        for (int kc2 = 0; kc2 < 2; ++kc2) {
            int kc = 2 * w + kc2;
            unsigned inner = (unsigned)(kc * 64 + lg * 16) ^ ((lm & 7) << 4);
            s16x8 ef = *(const s16x8*)(buf + lm * 512 + inner);
            size_t cb = (size_t)(chunk0 + kc) * 4;
            s16x8 a0 = *(const s16x8*)(ATF + ((cb + 0) * 64 + l) * 8);
            s16x8 a1 = *(const s16x8*)(ATF + ((cb + 1) * 64 + l) * 8);
            s16x8 a2 = *(const s16x8*)(ATF + ((cb + 2) * 64 + l) * 8);
            s16x8 a3 = *(const s16x8*)(ATF + ((cb + 3) * 64 + l) * 8);
            D0 = __builtin_amdgcn_mfma_f32_16x16x32_bf16(ef, a0, D0, 0, 0, 0);
            D1 = __builtin_amdgcn_mfma_f32_16x16x32_bf16(ef, a1, D1, 0, 0, 0);
            D2 = __builtin_amdgcn_mfma_f32_16x16x32_bf16(ef, a2, D2, 0, 0, 0);
            D3 = __builtin_amdgcn_mfma_f32_16x16x32_bf16(ef, a3, D3, 0, 0, 0);
            Dr = __builtin_amdgcn_mfma_f32_16x16x32_bf16(ef, ONES, Dr, 0, 0, 0);
        }

        // ---- per-tile deposits: rowsum partials + within dot ----
        int r0 = ibase + TM * t;
        if (lm == 0) {
#pragma unroll
            for (int r = 0; r < 4; ++r)
                atomicAdd(&rowsum[r0 + 4 * lg + r], Dr[r]);
        }
        const float* Ab = A + (size_t)(r0 + 4 * lg) * NK + lm;
#pragma unroll
        for (int r = 0; r < 4; ++r) {
            const float* ar = Ab + (size_t)r * NK;
            wsum += D0[r] * ar[0] + D1[r] * ar[16] + D2[r] * ar[32] + D3[r] * ar[48];
        }
        // no second barrier: next tile writes buf[(t+1)&1]; reuse of this buf
        // (t+2) is fenced by the single barrier at t+1 (all waves must arrive,
        // which requires finishing their t-reads first).
    }

    // ---- block epilogue: colsum combine + within reduce ----
    f32x4 cv = { creg0, creg1, creg2, creg3 };
    *(f32x4*)&csum[w][l * 4] = cv;
#pragma unroll
    for (int m = 1; m < 64; m <<= 1) wsum += __shfl_xor(wsum, m);
    if (l == 0) red[w] = wsum;
    __syncthreads();

    {
        int c = tid;  // 256 threads, 256 cols
        float s = (csum[0][c] + csum[1][c]) + (csum[2][c] + csum[3][c]);
        atomicAdd(&colsum[jbase + c], s);
    }
    if (tid == 0) within_part[bid] = red[0] + red[1] + red[2] + red[3];
}

// ---------- spatial pass 1: argmax ids + counts + coord sums ----------
__global__ __launch_bounds__(256) void spatial1(
    const float* __restrict__ A, const float* __restrict__ pos,
    int* __restrict__ ids, float* __restrict__ counts, float* __restrict__ sums)
{
    int wv = threadIdx.x >> 6, l = threadIdx.x & 63;
    int node = blockIdx.x * 4 + wv;
    float v = A[(size_t)node * NK + l];
    int idx = l;
#pragma unroll
    for (int m = 1; m < 64; m <<= 1) {
        float ov = __shfl_xor(v, m);
        int oi = __shfl_xor(idx, m);
        if (ov > v || (ov == v && oi < idx)) { v = ov; idx = oi; }
    }
    if (l == 0) {
        ids[node] = idx;
        atomicAdd(&counts[idx], 1.0f);
        atomicAdd(&sums[idx * 2 + 0], pos[(size_t)node * 2 + 0]);
        atomicAdd(&sums[idx * 2 + 1], pos[(size_t)node * 2 + 1]);
    }
}

// ---------- spatial pass 2: distances to centroids ----------
__global__ __launch_bounds__(256) void spatial2(
    const int* __restrict__ ids, const float* __restrict__ pos,
    const float* __restrict__ counts, const float* __restrict__ sums,
    float* __restrict__ distsum, int* __restrict__ maxid)
{
    __shared__ float ds[64];
    __shared__ int mx;
    int tid = threadIdx.x;
    if (tid < 64) ds[tid] = 0.f;
    if (tid == 0) mx = 0;
    __syncthreads();
    int i = blockIdx.x * 256 + tid;
    int id = ids[i];
    float den = counts[id] + EPSF;
    float cx = sums[id * 2 + 0] / den;
    float cy = sums[id * 2 + 1] / den;
    float dx = pos[(size_t)i * 2 + 0] - cx;
    float dy = pos[(size_t)i * 2 + 1] - cy;
    atomicAdd(&ds[id], sqrtf(dx * dx + dy * dy));
    atomicMax(&mx, id);
    __syncthreads();
    if (tid < 64) atomicAdd(&distsum[tid], ds[tid]);
    if (tid == 0) atomicMax(maxid, mx);
}

// ---------- finalize ----------
__global__ __launch_bounds__(256) void finalize(
    const float* __restrict__ rowsum, const float* __restrict__ colsum,
    const float* __restrict__ cons, const float* __restrict__ gen,
    const float* __restrict__ within_part, const float* __restrict__ counts,
    const float* __restrict__ distsum, const int* __restrict__ maxid,
    float* __restrict__ out)
{
    __shared__ float redb[4], rede[4], redw[4];
    int tid = threadIdx.x;
    int w = tid >> 6, l = tid & 63;
    float bacc = 0.f, eacc = 0.f, wacc = 0.f;
    for (int i = tid; i < NN; i += 256) {
        float imb = (cons[i] - gen[i]) - (colsum[i] - rowsum[i]);
        bacc += imb * imb;
        eacc += rowsum[i];
    }
    for (int i = tid; i < 1024; i += 256) wacc += within_part[i];
#pragma unroll
    for (int m = 1; m < 64; m <<= 1) {
        bacc += __shfl_xor(bacc, m);
        eacc += __shfl_xor(eacc, m);
        wacc += __shfl_xor(wacc, m);
    }
    if (l == 0) { redb[w] = bacc; rede[w] = eacc; redw[w] = wacc; }
    __syncthreads();

    float sacc = 0.f;
    if (tid < 64) {
        float c = counts[tid];
        float avg = distsum[tid] / (c + EPSF);
        sacc = (c >= 2.0f) ? avg : 0.f;
#pragma unroll
        for (int m = 1; m < 64; m <<= 1) sacc += __shfl_xor(sacc, m);
    }
    if (tid == 0) {
        float balance = (redb[0] + redb[1] + redb[2] + redb[3]) / (float)NN;
        float sumE = rede[0] + rede[1] + rede[2] + rede[3];
        float W = redw[0] + redw[1] + redw[2] + redw[3];
        float clustering = (sumE - 2.0f * W) / ((float)NN * (float)NN + EPSF);
        float nc = (float)(maxid[0] + 1) + EPSF;
        float spatial = sacc / nc;
        float total = 1.0f * balance + 0.5f * spatial + 0.3f * clustering;
        out[0] = total;
        out[1] = balance;
        out[2] = spatial;
        out[3] = clustering;
    }
}

extern "C" void kernel_launch(void* const* d_in, const int* in_sizes, int n_in,
                              void* d_out, int out_size, void* d_ws, size_t ws_size,
                              hipStream_t stream) {
    const float* E    = (const float*)d_in[0];
    const float* A    = (const float*)d_in[1];
    const float* pos  = (const float*)d_in[2];
    const float* cons = (const float*)d_in[3];
    const float* gen  = (const float*)d_in[4];
    float* out = (float*)d_out;

    char* ws = (char*)d_ws;
    unsigned short* ATF = (unsigned short*)ws;                // 1 MB fragment-major
    float* rowsum      = (float*)(ws + (size_t)2 * NK * NN);  // [N]
    float* colsum      = rowsum + NN;                         // [N]
    float* counts      = colsum + NN;                         // [64]
    float* sums        = counts + 64;                         // [64][2]
    float* distsum     = sums + 128;                          // [64]
    int*   maxid       = (int*)(distsum + 64);                // [1]
    float* within_part = (float*)(maxid + 1);                 // [1024]
    int*   ids         = (int*)(within_part + 1024);          // [N]

    size_t zbytes = ((size_t)NN * 2 + 64 + 128 + 64 + 1) * 4;
    hipMemsetAsync(rowsum, 0, zbytes, stream);

    cvt_at  <<<NN / 64, 256, 0, stream>>>(A, ATF);
    pass_e  <<<32 * 32, 256, 0, stream>>>(E, A, ATF, rowsum, colsum, within_part);
    spatial1<<<NN / 4, 256, 0, stream>>>(A, pos, ids, counts, sums);
    spatial2<<<NN / 256, 256, 0, stream>>>(ids, pos, counts, sums, distsum, maxid);
    finalize<<<1, 256, 0, stream>>>(rowsum, colsum, cons, gen, within_part, counts, distsum, maxid, out);
}

// Round 7
// 160.498 us; speedup vs baseline: 1.0982x; 1.0982x over previous
//
#include <hip/hip_runtime.h>
#include <hip/hip_bf16.h>
#include <math.h>

#define NN 8192      // nodes
#define NK 64        // clusters
#define EPSF 1e-6f
#define JW 256       // cols per block (j-window)
#define TR 32        // rows per tile
#define NTILE 8      // 8 tiles -> 256 rows per block
// grid: 32 j-strips x 32 i-groups = 1024 blocks, 256 threads (4 waves)
// K-permutation sigma(lg,e): e<4 -> 4*lg+e ; e>=4 -> 16+4*lg+(e-4)
// (order in which ds_read_b64_tr_b16 delivers tile rows; baked into ATF too)

typedef __attribute__((ext_vector_type(8))) short s16x8;
typedef __attribute__((ext_vector_type(4))) short s16x4;
typedef __attribute__((ext_vector_type(4))) float f32x4;

static __device__ __forceinline__ short f2bf(float x) {
    union { float f; unsigned u; } v; v.f = x;
    unsigned r = (v.u + 0x7fffu + ((v.u >> 16) & 1u)) >> 16;
    return (short)r;
}

// ---------- pre-kernel: A [N][64] f32 -> ATF (sigma-permuted B-fragments) ----------
// ATF[((c*4+nf)*64 + l)*8 + e] = bf16(A[32c + sigma(l>>4,e)][16nf + (l&15)])
__global__ __launch_bounds__(256) void cvt_at(const float* __restrict__ A,
                                              unsigned short* __restrict__ ATF) {
    __shared__ unsigned short T[64][72];   // [k][node-local]
    int tid = threadIdx.x;
    int n0 = blockIdx.x * 64;
    int node = tid >> 2;
    int k4 = (tid & 3) << 4;
    const float* ap = A + (size_t)(n0 + node) * NK + k4;
    f32x4 x0 = *(const f32x4*)(ap);
    f32x4 x1 = *(const f32x4*)(ap + 4);
    f32x4 x2 = *(const f32x4*)(ap + 8);
    f32x4 x3 = *(const f32x4*)(ap + 12);
#pragma unroll
    for (int e = 0; e < 4; ++e) {
        T[k4 + e][node]      = (unsigned short)f2bf(x0[e]);
        T[k4 + 4 + e][node]  = (unsigned short)f2bf(x1[e]);
        T[k4 + 8 + e][node]  = (unsigned short)f2bf(x2[e]);
        T[k4 + 12 + e][node] = (unsigned short)f2bf(x3[e]);
    }
    __syncthreads();
#pragma unroll
    for (int pass = 0; pass < 2; ++pass) {
        int oi = pass * 256 + tid;              // 512 outputs x 16B
        int l = oi & 63, nf = (oi >> 6) & 3, cl = oi >> 8;
        int lm = l & 15, lg = l >> 4;
        int k = 16 * nf + lm;
        int base = 32 * cl + 4 * lg;
        s16x8 v;
#pragma unroll
        for (int e = 0; e < 4; ++e) {
            v[e]     = (short)T[k][base + e];        // sigma, e<4
            v[e + 4] = (short)T[k][base + 16 + e];   // sigma, e>=4
        }
        size_t c = (size_t)blockIdx.x * 2 + cl;
        *(s16x8*)(ATF + ((c * 4 + nf) * 64 + l) * 8) = v;
    }
}

// ---------- main fused pass: G[j,k] orientation, persistent accumulators ----------
__global__ __launch_bounds__(256, 3) void pass_e(
    const float* __restrict__ E, const float* __restrict__ A,
    const unsigned short* __restrict__ ATF,
    float* __restrict__ rowsum, float* __restrict__ colsum,
    float* __restrict__ within_part)
{
    // tr-subtile layout: [16 colblocks][8 rowblocks][4 rows][16 cols] = 16KB/buf
    __shared__ unsigned short Ebf[2][8192];
    __shared__ float csum[4][JW];
    __shared__ float red[4];

    int tid = threadIdx.x;
    int w = tid >> 6, l = tid & 63;
    int bid = blockIdx.x;
    int jstrip = bid & 31;
    int ig = bid >> 5;
    int jbase = jstrip * JW;
    int ibase = ig * (TR * NTILE);
    int lm = l & 15, lg = l >> 4;

    f32x4 g[4][4];
#pragma unroll
    for (int mi = 0; mi < 4; ++mi)
#pragma unroll
        for (int nf = 0; nf < 4; ++nf) g[mi][nf] = f32x4{0.f, 0.f, 0.f, 0.f};

    float creg0 = 0.f, creg1 = 0.f, creg2 = 0.f, creg3 = 0.f;

    // stage addressing: wave w stages tile-rows 8w..8w+7; lane covers cols 4l..4l+3
    const float* ep = E + (size_t)(ibase + 8 * w) * NN + jbase + 4 * l;
    // ds_write byte addr within buf: cb(l>>2)*1024 + rb*128 + (rr&3)*32 + (l&3)*8
    unsigned wr_cb = (unsigned)(l >> 2) * 1024 + (unsigned)(l & 3) * 8;
    // tr-read per-lane addr: cb*1024 + 2*lm + 128*lg (+512 for rows 16..31)
    unsigned tr_lane = 2u * lm + 128u * lg + (unsigned)w * 4096;

    int qrow = 4 * (l & 1) + 2 * ((l >> 1) & 1) + ((l >> 2) & 1);
    bool b1 = (l & 1), b2 = (l & 2), b4 = (l & 4);

    f32x4 ld[8];
#pragma unroll
    for (int q = 0; q < 8; ++q) ld[q] = *(const f32x4*)(ep + (size_t)q * NN);

    for (int t = 0; t < NTILE; ++t) {
        unsigned short* buf = &Ebf[t & 1][0];
        unsigned bufoff = (unsigned)(size_t)buf;

        // ---- stage: colsum regs, rowsum partials, cvt, subtiled ds_write ----
        float r[8];
#pragma unroll
        for (int q = 0; q < 8; ++q) {
            f32x4 v = ld[q];
            creg0 += v[0]; creg1 += v[1]; creg2 += v[2]; creg3 += v[3];
            r[q] = (v[0] + v[1]) + (v[2] + v[3]);
            s16x4 b; b[0] = f2bf(v[0]); b[1] = f2bf(v[1]); b[2] = f2bf(v[2]); b[3] = f2bf(v[3]);
            int rr = 8 * w + q;
            *(s16x4*)((char*)buf + wr_cb + (unsigned)(rr >> 2) * 128 + (unsigned)(rr & 3) * 32) = b;
        }
        // rowsum halving reduce: 8 vals -> 1 per lane (rows of this wave), then 8-group sum
        float k0 = (b1 ? r[4] : r[0]) + __shfl_xor(b1 ? r[0] : r[4], 1);
        float k1 = (b1 ? r[5] : r[1]) + __shfl_xor(b1 ? r[1] : r[5], 1);
        float k2 = (b1 ? r[6] : r[2]) + __shfl_xor(b1 ? r[2] : r[6], 1);
        float k3 = (b1 ? r[7] : r[3]) + __shfl_xor(b1 ? r[3] : r[7], 1);
        float m0 = (b2 ? k2 : k0) + __shfl_xor(b2 ? k0 : k2, 2);
        float m1 = (b2 ? k3 : k1) + __shfl_xor(b2 ? k1 : k3, 2);
        float n0 = (b4 ? m1 : m0) + __shfl_xor(b4 ? m0 : m1, 4);
        n0 += __shfl_xor(n0, 8); n0 += __shfl_xor(n0, 16); n0 += __shfl_xor(n0, 32);
        if (l < 8) atomicAdd(&rowsum[ibase + 32 * t + 8 * w + qrow], n0);

        // ---- rendezvous: ds_writes visible, then one raw barrier ----
        asm volatile("s_waitcnt lgkmcnt(0)\n\ts_barrier" ::: "memory");

        // ---- issue next tile's loads (overlap with MFMA phase) ----
        if (t + 1 < NTILE) {
            const float* pn = ep + (size_t)(32 * (t + 1)) * NN;
#pragma unroll
            for (int q = 0; q < 8; ++q) ld[q] = *(const f32x4*)(pn + (size_t)q * NN);
        }

        // ---- transpose-read E fragments (T10), then MFMA into persistent G ----
        s16x4 lo[4], hi[4];
#pragma unroll
        for (int mi = 0; mi < 4; ++mi) {
            unsigned a = bufoff + tr_lane + (unsigned)mi * 1024;
            asm volatile("ds_read_b64_tr_b16 %0, %1" : "=&v"(lo[mi]) : "v"(a));
            asm volatile("ds_read_b64_tr_b16 %0, %1 offset:512" : "=&v"(hi[mi]) : "v"(a));
        }
        asm volatile("s_waitcnt lgkmcnt(0)" ::: "memory");
        __builtin_amdgcn_sched_barrier(0);

        size_t c = (size_t)(ig * 8 + t);
        s16x8 bf[4];
#pragma unroll
        for (int nf = 0; nf < 4; ++nf)
            bf[nf] = *(const s16x8*)(ATF + ((c * 4 + nf) * 64 + l) * 8);
#pragma unroll
        for (int mi = 0; mi < 4; ++mi) {
            s16x8 af;
#pragma unroll
            for (int e = 0; e < 4; ++e) { af[e] = lo[mi][e]; af[e + 4] = hi[mi][e]; }
#pragma unroll
            for (int nf = 0; nf < 4; ++nf)
                g[mi][nf] = __builtin_amdgcn_mfma_f32_16x16x32_bf16(af, bf[nf], g[mi][nf], 0, 0, 0);
        }
    }

    // ---- block epilogue: within dot (once), colsum combine ----
    float wsum = 0.f;
#pragma unroll
    for (int mi = 0; mi < 4; ++mi) {
        const float* Ar = A + (size_t)(jbase + 64 * w + 16 * mi + 4 * lg) * NK + lm;
#pragma unroll
        for (int rr = 0; rr < 4; ++rr)
#pragma unroll
            for (int nf = 0; nf < 4; ++nf)
                wsum += g[mi][nf][rr] * Ar[rr * NK + 16 * nf];
    }
#pragma unroll
    for (int m = 1; m < 64; m <<= 1) wsum += __shfl_xor(wsum, m);
    if (l == 0) red[w] = wsum;

    f32x4 cv = { creg0, creg1, creg2, creg3 };
    *(f32x4*)&csum[w][4 * l] = cv;
    __syncthreads();

    {
        int cix = tid;
        float s = (csum[0][cix] + csum[1][cix]) + (csum[2][cix] + csum[3][cix]);
        atomicAdd(&colsum[jbase + cix], s);
    }
    if (tid == 0) within_part[bid] = red[0] + red[1] + red[2] + red[3];
}

// ---------- spatial pass 1: argmax ids + counts + coord sums ----------
__global__ __launch_bounds__(256) void spatial1(
    const float* __restrict__ A, const float* __restrict__ pos,
    int* __restrict__ ids, float* __restrict__ counts, float* __restrict__ sums)
{
    int wv = threadIdx.x >> 6, l = threadIdx.x & 63;
    int node = blockIdx.x * 4 + wv;
    float v = A[(size_t)node * NK + l];
    int idx = l;
#pragma unroll
    for (int m = 1; m < 64; m <<= 1) {
        float ov = __shfl_xor(v, m);
        int oi = __shfl_xor(idx, m);
        if (ov > v || (ov == v && oi < idx)) { v = ov; idx = oi; }
    }
    if (l == 0) {
        ids[node] = idx;
        atomicAdd(&counts[idx], 1.0f);
        atomicAdd(&sums[idx * 2 + 0], pos[(size_t)node * 2 + 0]);
        atomicAdd(&sums[idx * 2 + 1], pos[(size_t)node * 2 + 1]);
    }
}

// ---------- spatial pass 2: distances to centroids ----------
__global__ __launch_bounds__(256) void spatial2(
    const int* __restrict__ ids, const float* __restrict__ pos,
    const float* __restrict__ counts, const float* __restrict__ sums,
    float* __restrict__ distsum, int* __restrict__ maxid)
{
    __shared__ float ds[64];
    __shared__ int mx;
    int tid = threadIdx.x;
    if (tid < 64) ds[tid] = 0.f;
    if (tid == 0) mx = 0;
    __syncthreads();
    int i = blockIdx.x * 256 + tid;
    int id = ids[i];
    float den = counts[id] + EPSF;
    float cx = sums[id * 2 + 0] / den;
    float cy = sums[id * 2 + 1] / den;
    float dx = pos[(size_t)i * 2 + 0] - cx;
    float dy = pos[(size_t)i * 2 + 1] - cy;
    atomicAdd(&ds[id], sqrtf(dx * dx + dy * dy));
    atomicMax(&mx, id);
    __syncthreads();
    if (tid < 64) atomicAdd(&distsum[tid], ds[tid]);
    if (tid == 0) atomicMax(maxid, mx);
}

// ---------- finalize ----------
__global__ __launch_bounds__(256) void finalize(
    const float* __restrict__ rowsum, const float* __restrict__ colsum,
    const float* __restrict__ cons, const float* __restrict__ gen,
    const float* __restrict__ within_part, const float* __restrict__ counts,
    const float* __restrict__ distsum, const int* __restrict__ maxid,
    float* __restrict__ out)
{
    __shared__ float redb[4], rede[4], redw[4];
    int tid = threadIdx.x;
    int w = tid >> 6, l = tid & 63;
    float bacc = 0.f, eacc = 0.f, wacc = 0.f;
    for (int i = tid; i < NN; i += 256) {
        float imb = (cons[i] - gen[i]) - (colsum[i] - rowsum[i]);
        bacc += imb * imb;
        eacc += rowsum[i];
    }
    for (int i = tid; i < 1024; i += 256) wacc += within_part[i];
#pragma unroll
    for (int m = 1; m < 64; m <<= 1) {
        bacc += __shfl_xor(bacc, m);
        eacc += __shfl_xor(eacc, m);
        wacc += __shfl_xor(wacc, m);
    }
    if (l == 0) { redb[w] = bacc; rede[w] = eacc; redw[w] = wacc; }
    __syncthreads();

    float sacc = 0.f;
    if (tid < 64) {
        float c = counts[tid];
        float avg = distsum[tid] / (c + EPSF);
        sacc = (c >= 2.0f) ? avg : 0.f;
#pragma unroll
        for (int m = 1; m < 64; m <<= 1) sacc += __shfl_xor(sacc, m);
    }
    if (tid == 0) {
        float balance = (redb[0] + redb[1] + redb[2] + redb[3]) / (float)NN;
        float sumE = rede[0] + rede[1] + rede[2] + rede[3];
        float W = redw[0] + redw[1] + redw[2] + redw[3];
        float clustering = (sumE - 2.0f * W) / ((float)NN * (float)NN + EPSF);
        float nc = (float)(maxid[0] + 1) + EPSF;
        float spatial = sacc / nc;
        float total = 1.0f * balance + 0.5f * spatial + 0.3f * clustering;
        out[0] = total;
        out[1] = balance;
        out[2] = spatial;
        out[3] = clustering;
    }
}

extern "C" void kernel_launch(void* const* d_in, const int* in_sizes, int n_in,
                              void* d_out, int out_size, void* d_ws, size_t ws_size,
                              hipStream_t stream) {
    const float* E    = (const float*)d_in[0];
    const float* A    = (const float*)d_in[1];
    const float* pos  = (const float*)d_in[2];
    const float* cons = (const float*)d_in[3];
    const float* gen  = (const float*)d_in[4];
    float* out = (float*)d_out;

    char* ws = (char*)d_ws;
    unsigned short* ATF = (unsigned short*)ws;                // 1 MB sigma-fragment-major
    float* rowsum      = (float*)(ws + (size_t)2 * NK * NN);  // [N]
    float* colsum      = rowsum + NN;                         // [N]
    float* counts      = colsum + NN;                         // [64]
    float* sums        = counts + 64;                         // [64][2]
    float* distsum     = sums + 128;                          // [64]
    int*   maxid       = (int*)(distsum + 64);                // [1]
    float* within_part = (float*)(maxid + 1);                 // [1024]
    int*   ids         = (int*)(within_part + 1024);          // [N]

    size_t zbytes = ((size_t)NN * 2 + 64 + 128 + 64 + 1) * 4;
    hipMemsetAsync(rowsum, 0, zbytes, stream);

    cvt_at  <<<NN / 64, 256, 0, stream>>>(A, ATF);
    pass_e  <<<32 * 32, 256, 0, stream>>>(E, A, ATF, rowsum, colsum, within_part);
    spatial1<<<NN / 4, 256, 0, stream>>>(A, pos, ids, counts, sums);
    spatial2<<<NN / 256, 256, 0, stream>>>(ids, pos, counts, sums, distsum, maxid);
    finalize<<<1, 256, 0, stream>>>(rowsum, colsum, cons, gen, within_part, counts, distsum, maxid, out);
}